// Round 7
// baseline (113.982 us; speedup 1.0000x reference)
//
#include <hip/hip_runtime.h>
#include <math.h>

namespace {
constexpr int KF  = 1152;   // padded feature dim (1120 used + 32 zeros)
constexpr int RPB = 4;      // rows per k_rest block (grid 512)
}

typedef __bf16 v8bf __attribute__((ext_vector_type(8)));
typedef float  v4f  __attribute__((ext_vector_type(4)));

__device__ __forceinline__ unsigned short f2bf(float f) {
    union { float f; unsigned u; } v; v.f = f;
    unsigned r = v.u + 0x7FFFu + ((v.u >> 16) & 1u);
    return (unsigned short)(r >> 16);
}

__device__ __forceinline__ v8bf as_v8bf(uint4 u) {
    union { uint4 u; v8bf b; } c; c.u = u; return c.b;
}

// ---------------------------------------------------------------------------
// K0: raw = silu(x@w1+b1) @ w2 + b2, tiled as a real GEMM.
// Root cause of the 43us k_feat: every one of 512 blocks streamed ALL 256KB
// of w2 (128MB aggregate, L2-latency-bound at ~2.6 B/cyc/block). Here each
// block computes a 32-row x 256-col tile of raw and reads only a 64x256 w2
// panel (64KB): total w2 traffic 16MB, coalesced float4, hidden under
// 2048 FMAs/thread of ILP. FMA order per output element is k=0..63
// ascending with b2 init — bitwise-identical to the verified kernel.
// Thread layout: wave wv owns rows r0=wv*8..+7 (h_s reads are lane-uniform
// broadcasts); lane owns col-quad c0+(t&63)*4 (w2 reads coalesced 1KB/instr).
// ---------------------------------------------------------------------------
__global__ __launch_bounds__(256) void k_raw(
    const float* __restrict__ Q, const float* __restrict__ K,
    const float* __restrict__ w1, const float* __restrict__ b1,
    const float* __restrict__ w2, const float* __restrict__ b2,
    float* __restrict__ rawOut)
{
    __shared__ __attribute__((aligned(16))) float x_s[32][32];
    __shared__ __attribute__((aligned(16))) float h_s[32][64];

    const int t    = threadIdx.x;
    const int lane = t & 63;
    const int wv   = t >> 6;              // 0..3
    const int gr0  = blockIdx.x * 32;     // row-tile base (0..2016)
    const int c0   = blockIdx.y * 256;    // col-tile base (0,256,512,768)

    // ---- load x tile: 32 rows x 32, float4 per thread
    {
        int r  = t >> 3;
        int i4 = (t & 7) * 4;
        int g  = gr0 + r;
        const float* src = (g < 1024) ? (Q + (size_t)g * 32)
                                      : (K + (size_t)(g - 1024) * 32);
        *(float4*)&x_s[r][i4] = *(const float4*)&src[i4];
    }
    __syncthreads();

    // ---- h = silu(x@w1+b1): lane j = lane, wave's 8 rows. w1 coalesced.
    {
        const int j  = lane;
        const int r0 = wv * 8;
        float bj = b1[j];
        float z[8];
        #pragma unroll
        for (int r = 0; r < 8; ++r) z[r] = bj;
        for (int i = 0; i < 32; ++i) {
            float wij = w1[i * 64 + j];
            #pragma unroll
            for (int r = 0; r < 8; ++r) z[r] = fmaf(x_s[r0 + r][i], wij, z[r]);
        }
        #pragma unroll
        for (int r = 0; r < 8; ++r)
            h_s[r0 + r][j] = z[r] / (1.0f + __expf(-z[r]));
    }
    __syncthreads();

    // ---- raw tile: thread = 8 rows x 4 cols, k ascending in quads
    {
        const int p  = c0 + lane * 4;
        const int r0 = wv * 8;
        float4 bq = *(const float4*)&b2[p];
        float acc[8][4];
        #pragma unroll
        for (int r = 0; r < 8; ++r) {
            acc[r][0] = bq.x; acc[r][1] = bq.y; acc[r][2] = bq.z; acc[r][3] = bq.w;
        }
        for (int kq = 0; kq < 16; ++kq) {
            float4 wrow[4];
            #pragma unroll
            for (int kk = 0; kk < 4; ++kk)
                wrow[kk] = *(const float4*)&w2[(size_t)(kq * 4 + kk) * 1024 + p];
            float4 hq[8];
            #pragma unroll
            for (int r = 0; r < 8; ++r)
                hq[r] = *(const float4*)&h_s[r0 + r][kq * 4];
            #pragma unroll
            for (int kk = 0; kk < 4; ++kk) {
                #pragma unroll
                for (int r = 0; r < 8; ++r) {
                    float hv = ((const float*)&hq[r])[kk];
                    acc[r][0] = fmaf(hv, wrow[kk].x, acc[r][0]);
                    acc[r][1] = fmaf(hv, wrow[kk].y, acc[r][1]);
                    acc[r][2] = fmaf(hv, wrow[kk].z, acc[r][2]);
                    acc[r][3] = fmaf(hv, wrow[kk].w, acc[r][3]);
                }
            }
        }
        #pragma unroll
        for (int r = 0; r < 8; ++r) {
            float4 o;
            o.x = acc[r][0]; o.y = acc[r][1]; o.z = acc[r][2]; o.w = acc[r][3];
            *(float4*)&rawOut[(size_t)(gr0 + r0 + r) * 1024 + p] = o;
        }
    }
}

// ---------------------------------------------------------------------------
// K1: per-row feature builder (raw precomputed by k_raw). 4 rows/block,
// 256 threads, grid 512. Identical to the verified round-1 k_feat with the
// h / h@w2 stages replaced by a coalesced float4 load of raw.
// ---------------------------------------------------------------------------
__global__ __launch_bounds__(256) void k_rest(
    const float* __restrict__ Q, const float* __restrict__ K,
    const float* __restrict__ rawIn,
    unsigned short* __restrict__ featA, unsigned short* __restrict__ featB,
    float* __restrict__ cOut)
{
    __shared__ __attribute__((aligned(16))) float x_s[RPB][32];
    __shared__ __attribute__((aligned(16))) float L_s[RPB][32][36];
    __shared__ __attribute__((aligned(16))) float G_s[RPB][528];   // col-major packed
    __shared__ __attribute__((aligned(16))) float u_s[RPB][32];
    __shared__ unsigned short tri_s[528];                          // (i<<8)|j

    const int t  = threadIdx.x;
    const int g0 = blockIdx.x * RPB;

    // ---- triangular index table (once)
    for (int pr = t; pr < 528; pr += 256) {
        int j = (int)((65.0f - sqrtf(4225.0f - 8.0f * (float)pr)) * 0.5f);
        while (j > 0 && j * (65 - j) / 2 > pr) --j;
        while ((j + 1) * (64 - j) / 2 <= pr) ++j;
        int i = j + (pr - j * (65 - j) / 2);
        tri_s[pr] = (unsigned short)((i << 8) | j);
    }
    // ---- load x
    if (t < RPB * 32) {
        int r = t >> 5, i = t & 31;
        int g = g0 + r;
        const float* src = (g < 1024) ? (Q + (size_t)g * 32)
                                      : (K + (size_t)(g - 1024) * 32);
        x_s[r][i] = src[i];
    }

    // ---- raw -> L.  Thread t owns p-quad [4t,4t+4), all 4 rows.
    {
        const int p4 = t * 4;
        const int i  = p4 >> 5;
        const int j0 = p4 & 31;
        #pragma unroll
        for (int r = 0; r < RPB; ++r) {
            float4 rq = *(const float4*)&rawIn[(size_t)(g0 + r) * 1024 + p4];
            const float* ra = (const float*)&rq;
            float4 lv;
            float* lvp = (float*)&lv;
            #pragma unroll
            for (int e = 0; e < 4; ++e) {
                int j = j0 + e;
                float raw = ra[e];
                float ex = __expf(0.4f * raw);
                float c5 = 5.0f * (ex - 1.0f) / (ex + 1.0f);   // 5*tanh(raw/5)
                float val;
                if (i < j)       val = 0.0f;
                else if (i == j) { float z = c5 + 1.0f; val = log1pf(__expf(z)) + 1e-4f; }
                else             val = c5;
                lvp[e] = val;
            }
            *(float4*)&L_s[r][i][j0] = lv;
        }
    }
    __syncthreads();

    // ---- G = L L^T (lower triangle, packed column-major)
    for (int idx = t; idx < RPB * 528; idx += 256) {
        int r  = idx / 528;
        int pr = idx - r * 528;
        int tv = tri_s[pr];
        int i = tv >> 8, j = tv & 255;
        const float* Li = &L_s[r][i][0];
        const float* Lj = &L_s[r][j][0];
        float s = 0.0f;
        int nf = (j + 1) >> 2;
        for (int q = 0; q < nf; ++q) {
            float4 a  = *(const float4*)&Li[q * 4];
            float4 bb = *(const float4*)&Lj[q * 4];
            s += a.x * bb.x + a.y * bb.y + a.z * bb.z + a.w * bb.w;
        }
        for (int tt = nf * 4; tt <= j; ++tt) s = fmaf(Li[tt], Lj[tt], s);
        G_s[r][pr] = s;
    }
    __syncthreads();

    // ---- u = G x
    if (t < RPB * 32) {
        int r = t >> 5, i = t & 31;
        float s = 0.0f;
        #pragma unroll
        for (int j = 0; j < 32; ++j) {
            float gv = (j <= i) ? G_s[r][j * (65 - j) / 2 + i - j]
                                : G_s[r][i * (65 - i) / 2 + j - i];
            s = fmaf(gv, x_s[r][j], s);
        }
        u_s[r][i] = s;
    }
    __syncthreads();

    // ---- c = u . x
    if (t < RPB) {
        float s = 0.0f;
        #pragma unroll
        for (int i = 0; i < 32; ++i) s = fmaf(u_s[t][i], x_s[t][i], s);
        cOut[g0 + t] = s;
    }

    // ---- feature write: quads of 4 bf16, packed uint2 stores (coalesced).
    for (int idx = t; idx < RPB * (KF / 4); idx += 256) {
        int r   = idx / (KF / 4);
        int q   = idx - r * (KF / 4);
        int pos = q * 4;
        int g   = g0 + r;
        bool isA = (g < 1024);
        unsigned short* dst = isA ? (featA + (size_t)g * KF)
                                  : (featB + (size_t)(g - 1024) * KF);
        unsigned short ev[4];
        #pragma unroll
        for (int e = 0; e < 4; ++e) {
            int p = pos + e;
            float va;
            if (p < 1056) {
                int pr = (p < 528) ? p : p - 528;
                bool wantG = (p < 528) ? isA : !isA;
                int tv = tri_s[pr];
                int i = tv >> 8, j = tv & 255;
                float gv = G_s[r][pr] * ((i == j) ? 1.0f : 2.0f);
                float ov = x_s[r][i] * x_s[r][j];
                va = wantG ? gv : ov;
            } else if (p < 1088) {
                int i = p - 1056;
                va = isA ? u_s[r][i] : -2.0f * x_s[r][i];
            } else if (p < 1120) {
                int i = p - 1088;
                va = isA ? x_s[r][i] : -2.0f * u_s[r][i];
            } else {
                va = 0.0f;   // ws re-poisoned 0xAA — pad must be written
            }
            ev[e] = f2bf(va);
        }
        uint2 w;
        w.x = (unsigned)ev[0] | ((unsigned)ev[1] << 16);
        w.y = (unsigned)ev[2] | ((unsigned)ev[3] << 16);
        *(uint2*)(dst + pos) = w;
    }
}

// ---------------------------------------------------------------------------
// K2: out = sqrt(clip(0.5*(cA+cB+A.B))). In-block split-K (verified round-1
// version, unchanged): 256 threads = 4 waves per 32x32 tile; wave w owns
// K-chunk [w*288,(w+1)*288), depth-4 register prefetch, LDS reduction with
// fused epilogue. 512 blocks -> 8 waves/CU. Bijective XCD swizzle.
// ---------------------------------------------------------------------------
__global__ __launch_bounds__(256) void k_gemm(
    const unsigned short* __restrict__ featA,
    const unsigned short* __restrict__ featB,
    const float* __restrict__ cOut,
    float* __restrict__ out)
{
    __shared__ __attribute__((aligned(16))) float red[4][32][36];  // +4 pad

    const int t    = threadIdx.x;
    const int lane = t & 63;
    const int w    = t >> 6;          // wave id 0..3 = K-chunk id

    // bijective XCD swizzle over 512 blocks (512 % 8 == 0)
    const int lin = blockIdx.x;
    const int swz = (lin & 7) * 64 + (lin >> 3);
    const int m0 = (swz & 15) * 32;
    const int n0 = ((swz >> 4) & 15) * 32;
    const int b  = swz >> 8;

    const int fr = lane & 15;
    const int fq = lane >> 4;
    const int kbase = w * 288 + fq * 8;     // this wave's K-chunk start

    const unsigned short* pA0 = featA + (size_t)(b * 512 + n0 + fr) * KF + kbase;
    const unsigned short* pA1 = pA0 + (size_t)16 * KF;
    const unsigned short* pB0 = featB + (size_t)(b * 512 + m0 + fr) * KF + kbase;
    const unsigned short* pB1 = pB0 + (size_t)16 * KF;

    v4f acc00 = {0,0,0,0}, acc01 = {0,0,0,0}, acc10 = {0,0,0,0}, acc11 = {0,0,0,0};

    // depth-4 register prefetch over this wave's 9 k-steps
    uint4 bA0[4], bA1[4], bB0[4], bB1[4];
    #pragma unroll
    for (int s = 0; s < 4; ++s) {
        bA0[s] = *(const uint4*)(pA0 + s * 32);
        bA1[s] = *(const uint4*)(pA1 + s * 32);
        bB0[s] = *(const uint4*)(pB0 + s * 32);
        bB1[s] = *(const uint4*)(pB1 + s * 32);
    }

    #pragma unroll
    for (int s = 0; s < 9; ++s) {
        const int slot = s & 3;
        v8bf a0  = as_v8bf(bA0[slot]);
        v8bf a1  = as_v8bf(bA1[slot]);
        v8bf b0v = as_v8bf(bB0[slot]);
        v8bf b1v = as_v8bf(bB1[slot]);
        const int kn = s + 4;
        if (kn < 9) {
            bA0[slot] = *(const uint4*)(pA0 + kn * 32);
            bA1[slot] = *(const uint4*)(pA1 + kn * 32);
            bB0[slot] = *(const uint4*)(pB0 + kn * 32);
            bB1[slot] = *(const uint4*)(pB1 + kn * 32);
        }
        acc00 = __builtin_amdgcn_mfma_f32_16x16x32_bf16(a0, b0v, acc00, 0, 0, 0);
        acc01 = __builtin_amdgcn_mfma_f32_16x16x32_bf16(a0, b1v, acc01, 0, 0, 0);
        acc10 = __builtin_amdgcn_mfma_f32_16x16x32_bf16(a1, b0v, acc10, 0, 0, 0);
        acc11 = __builtin_amdgcn_mfma_f32_16x16x32_bf16(a1, b1v, acc11, 0, 0, 0);
    }

    // ---- deposit partial tile: D elem (lane,v): row n_l = (lane>>4)*4+v, col m_l = lane&15
    #pragma unroll
    for (int v = 0; v < 4; ++v) {
        red[w][fq * 4 + v][fr]           = acc00[v];
        red[w][fq * 4 + v][fr + 16]      = acc01[v];
        red[w][16 + fq * 4 + v][fr]      = acc10[v];
        red[w][16 + fq * 4 + v][fr + 16] = acc11[v];
    }
    __syncthreads();

    // ---- reduce 4 K-chunks + epilogue. Thread t: row n_l = t>>3, cols m_l0..+3.
    const int n_l  = t >> 3;
    const int m_l0 = (t & 7) * 4;
    float4 s0 = *(const float4*)&red[0][n_l][m_l0];
    float4 s1 = *(const float4*)&red[1][n_l][m_l0];
    float4 s2 = *(const float4*)&red[2][n_l][m_l0];
    float4 s3 = *(const float4*)&red[3][n_l][m_l0];

    const int   n_g = n0 + n_l;
    const float cA  = cOut[b * 512 + n_g];
    const float4 cB = *(const float4*)&cOut[1024 + b * 512 + m0 + m_l0];

    float4 res;
    {
        float tot[4] = { s0.x + s1.x + s2.x + s3.x,
                         s0.y + s1.y + s2.y + s3.y,
                         s0.z + s1.z + s2.z + s3.z,
                         s0.w + s1.w + s2.w + s3.w };
        const float cb[4] = { cB.x, cB.y, cB.z, cB.w };
        float* rp = (float*)&res;
        #pragma unroll
        for (int e = 0; e < 4; ++e) {
            float dsq = 0.5f * (tot[e] + cA + cb[e]);
            dsq = fminf(fmaxf(dsq, 1e-6f), 1e6f);
            rp[e] = sqrtf(dsq);
        }
    }
    *(float4*)&out[((size_t)(b * 512 + n_g)) * 512 + m0 + m_l0] = res;
}

// ---------------------------------------------------------------------------
extern "C" void kernel_launch(void* const* d_in, const int* in_sizes, int n_in,
                              void* d_out, int out_size, void* d_ws, size_t ws_size,
                              hipStream_t stream)
{
    const float* Q  = (const float*)d_in[0];
    const float* K  = (const float*)d_in[1];
    const float* w1 = (const float*)d_in[2];
    const float* b1 = (const float*)d_in[3];
    const float* w2 = (const float*)d_in[4];
    const float* b2 = (const float*)d_in[5];
    float* out = (float*)d_out;

    unsigned short* featA = (unsigned short*)d_ws;            // [1024][1152] bf16
    unsigned short* featB = featA + (size_t)1024 * KF;        // [1024][1152] bf16
    float* cOut = (float*)(featB + (size_t)1024 * KF);        // [2048] fp32
    float* raw  = cOut + 2048;                                // [2048][1024] fp32

    k_raw<<<dim3(64, 4), dim3(256), 0, stream>>>(Q, K, w1, b1, w2, b2, raw);
    k_rest<<<dim3(2048 / RPB), dim3(256), 0, stream>>>(Q, K, raw, featA, featB, cOut);
    k_gemm<<<dim3(512), dim3(256), 0, stream>>>(featA, featB, cOut, out);
}

// Round 8
// 113.634 us; speedup vs baseline: 1.0031x; 1.0031x over previous
//
#include <hip/hip_runtime.h>
#include <math.h>

namespace {
constexpr int KF  = 1152;   // padded feature dim (1120 used + 32 zeros)
constexpr int RPB = 4;      // rows per k_feat block
}

typedef __bf16 v8bf __attribute__((ext_vector_type(8)));
typedef float  v4f  __attribute__((ext_vector_type(4)));

__device__ __forceinline__ unsigned short f2bf(float f) {
    union { float f; unsigned u; } v; v.f = f;
    unsigned r = v.u + 0x7FFFu + ((v.u >> 16) & 1u);
    return (unsigned short)(r >> 16);
}

__device__ __forceinline__ v8bf as_v8bf(uint4 u) {
    union { uint4 u; v8bf b; } c; c.u = u; return c.b;
}

// ---------------------------------------------------------------------------
// K0 (PROBE): raw = silu(x@w1+b1)@w2+b2, tiled GEMM — identical structure to
// round 7's k_raw plus unroll hygiene. Its output is NOT consumed this round;
// it exists to measure its true cost as (dur - 101 - gap), cleanly separated
// from k_rest. R7's 3-kernel pipeline cost ~61us against a ~20us model and
// no kernel broke the 40.5us top-5 cutoff — this isolates k_raw's share.
// ---------------------------------------------------------------------------
__global__ __launch_bounds__(256) void k_raw(
    const float* __restrict__ Q, const float* __restrict__ K,
    const float* __restrict__ w1, const float* __restrict__ b1,
    const float* __restrict__ w2, const float* __restrict__ b2,
    float* __restrict__ rawOut)
{
    __shared__ __attribute__((aligned(16))) float x_s[32][32];
    __shared__ __attribute__((aligned(16))) float h_s[32][64];

    const int t    = threadIdx.x;
    const int lane = t & 63;
    const int wv   = t >> 6;              // 0..3
    const int gr0  = blockIdx.x * 32;     // row-tile base
    const int c0   = blockIdx.y * 256;    // col-tile base

    {
        int r  = t >> 3;
        int i4 = (t & 7) * 4;
        int g  = gr0 + r;
        const float* src = (g < 1024) ? (Q + (size_t)g * 32)
                                      : (K + (size_t)(g - 1024) * 32);
        *(float4*)&x_s[r][i4] = *(const float4*)&src[i4];
    }
    __syncthreads();

    {
        const int j  = lane;
        const int r0 = wv * 8;
        float bj = b1[j];
        float z[8];
        #pragma unroll
        for (int r = 0; r < 8; ++r) z[r] = bj;
        #pragma unroll
        for (int i = 0; i < 32; ++i) {
            float wij = w1[i * 64 + j];
            #pragma unroll
            for (int r = 0; r < 8; ++r) z[r] = fmaf(x_s[r0 + r][i], wij, z[r]);
        }
        #pragma unroll
        for (int r = 0; r < 8; ++r)
            h_s[r0 + r][j] = z[r] / (1.0f + __expf(-z[r]));
    }
    __syncthreads();

    {
        const int p  = c0 + lane * 4;
        const int r0 = wv * 8;
        float4 bq = *(const float4*)&b2[p];
        float acc[8][4];
        #pragma unroll
        for (int r = 0; r < 8; ++r) {
            acc[r][0] = bq.x; acc[r][1] = bq.y; acc[r][2] = bq.z; acc[r][3] = bq.w;
        }
        #pragma unroll
        for (int kq = 0; kq < 16; ++kq) {
            float4 wrow[4];
            #pragma unroll
            for (int kk = 0; kk < 4; ++kk)
                wrow[kk] = *(const float4*)&w2[(size_t)(kq * 4 + kk) * 1024 + p];
            float4 hq[8];
            #pragma unroll
            for (int r = 0; r < 8; ++r)
                hq[r] = *(const float4*)&h_s[r0 + r][kq * 4];
            #pragma unroll
            for (int kk = 0; kk < 4; ++kk) {
                #pragma unroll
                for (int r = 0; r < 8; ++r) {
                    float hv = ((const float*)&hq[r])[kk];
                    acc[r][0] = fmaf(hv, wrow[kk].x, acc[r][0]);
                    acc[r][1] = fmaf(hv, wrow[kk].y, acc[r][1]);
                    acc[r][2] = fmaf(hv, wrow[kk].z, acc[r][2]);
                    acc[r][3] = fmaf(hv, wrow[kk].w, acc[r][3]);
                }
            }
        }
        #pragma unroll
        for (int r = 0; r < 8; ++r) {
            float4 o;
            o.x = acc[r][0]; o.y = acc[r][1]; o.z = acc[r][2]; o.w = acc[r][3];
            *(float4*)&rawOut[(size_t)(gr0 + r0 + r) * 1024 + p] = o;
        }
    }
}

// ---------------------------------------------------------------------------
// K1: per-row feature builder — EXACT round-1 verified version (101.1us
// configuration). Recomputes h and h@w2 itself; ignores k_raw's output.
// ---------------------------------------------------------------------------
__global__ __launch_bounds__(256) void k_feat(
    const float* __restrict__ Q, const float* __restrict__ K,
    const float* __restrict__ w1, const float* __restrict__ b1,
    const float* __restrict__ w2, const float* __restrict__ b2,
    unsigned short* __restrict__ featA, unsigned short* __restrict__ featB,
    float* __restrict__ cOut)
{
    __shared__ __attribute__((aligned(16))) float x_s[RPB][32];
    __shared__ __attribute__((aligned(16))) float h_s[RPB][64];
    __shared__ __attribute__((aligned(16))) float L_s[RPB][32][36];
    __shared__ __attribute__((aligned(16))) float G_s[RPB][528];   // col-major packed
    __shared__ __attribute__((aligned(16))) float u_s[RPB][32];
    __shared__ unsigned short tri_s[528];                          // (i<<8)|j

    const int t  = threadIdx.x;
    const int g0 = blockIdx.x * RPB;

    for (int pr = t; pr < 528; pr += 256) {
        int j = (int)((65.0f - sqrtf(4225.0f - 8.0f * (float)pr)) * 0.5f);
        while (j > 0 && j * (65 - j) / 2 > pr) --j;
        while ((j + 1) * (64 - j) / 2 <= pr) ++j;
        int i = j + (pr - j * (65 - j) / 2);
        tri_s[pr] = (unsigned short)((i << 8) | j);
    }
    if (t < RPB * 32) {
        int r = t >> 5, i = t & 31;
        int g = g0 + r;
        const float* src = (g < 1024) ? (Q + (size_t)g * 32)
                                      : (K + (size_t)(g - 1024) * 32);
        x_s[r][i] = src[i];
    }
    __syncthreads();

    {
        int r = t >> 6, j = t & 63;
        float z = b1[j];
        #pragma unroll
        for (int i = 0; i < 32; ++i) z = fmaf(x_s[r][i], w1[i * 64 + j], z);
        h_s[r][j] = z / (1.0f + __expf(-z));
    }
    __syncthreads();

    {
        const int p4 = t * 4;
        float acc[RPB][4];
        float4 bq = *(const float4*)&b2[p4];
        #pragma unroll
        for (int r = 0; r < RPB; ++r) {
            acc[r][0] = bq.x; acc[r][1] = bq.y; acc[r][2] = bq.z; acc[r][3] = bq.w;
        }
        for (int jb = 0; jb < 8; ++jb) {
            float h8[RPB][8];
            #pragma unroll
            for (int r = 0; r < RPB; ++r) {
                *(float4*)&h8[r][0] = *(const float4*)&h_s[r][jb * 8 + 0];
                *(float4*)&h8[r][4] = *(const float4*)&h_s[r][jb * 8 + 4];
            }
            #pragma unroll
            for (int jj = 0; jj < 8; ++jj) {
                float4 w = *(const float4*)&w2[(size_t)(jb * 8 + jj) * 1024 + p4];
                #pragma unroll
                for (int r = 0; r < RPB; ++r) {
                    acc[r][0] = fmaf(h8[r][jj], w.x, acc[r][0]);
                    acc[r][1] = fmaf(h8[r][jj], w.y, acc[r][1]);
                    acc[r][2] = fmaf(h8[r][jj], w.z, acc[r][2]);
                    acc[r][3] = fmaf(h8[r][jj], w.w, acc[r][3]);
                }
            }
        }
        const int i  = p4 >> 5;
        const int j0 = p4 & 31;
        #pragma unroll
        for (int r = 0; r < RPB; ++r) {
            float4 lv;
            float* lvp = (float*)&lv;
            #pragma unroll
            for (int e = 0; e < 4; ++e) {
                int j = j0 + e;
                float raw = acc[r][e];
                float ex = __expf(0.4f * raw);
                float c5 = 5.0f * (ex - 1.0f) / (ex + 1.0f);   // 5*tanh(raw/5)
                float val;
                if (i < j)       val = 0.0f;
                else if (i == j) { float z = c5 + 1.0f; val = log1pf(__expf(z)) + 1e-4f; }
                else             val = c5;
                lvp[e] = val;
            }
            *(float4*)&L_s[r][i][j0] = lv;
        }
    }
    __syncthreads();

    for (int idx = t; idx < RPB * 528; idx += 256) {
        int r  = idx / 528;
        int pr = idx - r * 528;
        int tv = tri_s[pr];
        int i = tv >> 8, j = tv & 255;
        const float* Li = &L_s[r][i][0];
        const float* Lj = &L_s[r][j][0];
        float s = 0.0f;
        int nf = (j + 1) >> 2;
        for (int q = 0; q < nf; ++q) {
            float4 a  = *(const float4*)&Li[q * 4];
            float4 bb = *(const float4*)&Lj[q * 4];
            s += a.x * bb.x + a.y * bb.y + a.z * bb.z + a.w * bb.w;
        }
        for (int tt = nf * 4; tt <= j; ++tt) s = fmaf(Li[tt], Lj[tt], s);
        G_s[r][pr] = s;
    }
    __syncthreads();

    if (t < RPB * 32) {
        int r = t >> 5, i = t & 31;
        float s = 0.0f;
        #pragma unroll
        for (int j = 0; j < 32; ++j) {
            float gv = (j <= i) ? G_s[r][j * (65 - j) / 2 + i - j]
                                : G_s[r][i * (65 - i) / 2 + j - i];
            s = fmaf(gv, x_s[r][j], s);
        }
        u_s[r][i] = s;
    }
    __syncthreads();

    if (t < RPB) {
        float s = 0.0f;
        #pragma unroll
        for (int i = 0; i < 32; ++i) s = fmaf(u_s[t][i], x_s[t][i], s);
        cOut[g0 + t] = s;
    }

    for (int idx = t; idx < RPB * (KF / 4); idx += 256) {
        int r   = idx / (KF / 4);
        int q   = idx - r * (KF / 4);
        int pos = q * 4;
        int g   = g0 + r;
        bool isA = (g < 1024);
        unsigned short* dst = isA ? (featA + (size_t)g * KF)
                                  : (featB + (size_t)(g - 1024) * KF);
        unsigned short ev[4];
        #pragma unroll
        for (int e = 0; e < 4; ++e) {
            int p = pos + e;
            float va;
            if (p < 1056) {
                int pr = (p < 528) ? p : p - 528;
                bool wantG = (p < 528) ? isA : !isA;
                int tv = tri_s[pr];
                int i = tv >> 8, j = tv & 255;
                float gv = G_s[r][pr] * ((i == j) ? 1.0f : 2.0f);
                float ov = x_s[r][i] * x_s[r][j];
                va = wantG ? gv : ov;
            } else if (p < 1088) {
                int i = p - 1056;
                va = isA ? u_s[r][i] : -2.0f * x_s[r][i];
            } else if (p < 1120) {
                int i = p - 1088;
                va = isA ? x_s[r][i] : -2.0f * u_s[r][i];
            } else {
                va = 0.0f;   // ws re-poisoned 0xAA — pad must be written
            }
            ev[e] = f2bf(va);
        }
        uint2 w;
        w.x = (unsigned)ev[0] | ((unsigned)ev[1] << 16);
        w.y = (unsigned)ev[2] | ((unsigned)ev[3] << 16);
        *(uint2*)(dst + pos) = w;
    }
}

// ---------------------------------------------------------------------------
// K2: verified round-1 split-K MFMA GEMM + epilogue (unchanged).
// ---------------------------------------------------------------------------
__global__ __launch_bounds__(256) void k_gemm(
    const unsigned short* __restrict__ featA,
    const unsigned short* __restrict__ featB,
    const float* __restrict__ cOut,
    float* __restrict__ out)
{
    __shared__ __attribute__((aligned(16))) float red[4][32][36];  // +4 pad

    const int t    = threadIdx.x;
    const int lane = t & 63;
    const int w    = t >> 6;          // wave id 0..3 = K-chunk id

    const int lin = blockIdx.x;
    const int swz = (lin & 7) * 64 + (lin >> 3);
    const int m0 = (swz & 15) * 32;
    const int n0 = ((swz >> 4) & 15) * 32;
    const int b  = swz >> 8;

    const int fr = lane & 15;
    const int fq = lane >> 4;
    const int kbase = w * 288 + fq * 8;

    const unsigned short* pA0 = featA + (size_t)(b * 512 + n0 + fr) * KF + kbase;
    const unsigned short* pA1 = pA0 + (size_t)16 * KF;
    const unsigned short* pB0 = featB + (size_t)(b * 512 + m0 + fr) * KF + kbase;
    const unsigned short* pB1 = pB0 + (size_t)16 * KF;

    v4f acc00 = {0,0,0,0}, acc01 = {0,0,0,0}, acc10 = {0,0,0,0}, acc11 = {0,0,0,0};

    uint4 bA0[4], bA1[4], bB0[4], bB1[4];
    #pragma unroll
    for (int s = 0; s < 4; ++s) {
        bA0[s] = *(const uint4*)(pA0 + s * 32);
        bA1[s] = *(const uint4*)(pA1 + s * 32);
        bB0[s] = *(const uint4*)(pB0 + s * 32);
        bB1[s] = *(const uint4*)(pB1 + s * 32);
    }

    #pragma unroll
    for (int s = 0; s < 9; ++s) {
        const int slot = s & 3;
        v8bf a0  = as_v8bf(bA0[slot]);
        v8bf a1  = as_v8bf(bA1[slot]);
        v8bf b0v = as_v8bf(bB0[slot]);
        v8bf b1v = as_v8bf(bB1[slot]);
        const int kn = s + 4;
        if (kn < 9) {
            bA0[slot] = *(const uint4*)(pA0 + kn * 32);
            bA1[slot] = *(const uint4*)(pA1 + kn * 32);
            bB0[slot] = *(const uint4*)(pB0 + kn * 32);
            bB1[slot] = *(const uint4*)(pB1 + kn * 32);
        }
        acc00 = __builtin_amdgcn_mfma_f32_16x16x32_bf16(a0, b0v, acc00, 0, 0, 0);
        acc01 = __builtin_amdgcn_mfma_f32_16x16x32_bf16(a0, b1v, acc01, 0, 0, 0);
        acc10 = __builtin_amdgcn_mfma_f32_16x16x32_bf16(a1, b0v, acc10, 0, 0, 0);
        acc11 = __builtin_amdgcn_mfma_f32_16x16x32_bf16(a1, b1v, acc11, 0, 0, 0);
    }

    #pragma unroll
    for (int v = 0; v < 4; ++v) {
        red[w][fq * 4 + v][fr]           = acc00[v];
        red[w][fq * 4 + v][fr + 16]      = acc01[v];
        red[w][16 + fq * 4 + v][fr]      = acc10[v];
        red[w][16 + fq * 4 + v][fr + 16] = acc11[v];
    }
    __syncthreads();

    const int n_l  = t >> 3;
    const int m_l0 = (t & 7) * 4;
    float4 s0 = *(const float4*)&red[0][n_l][m_l0];
    float4 s1 = *(const float4*)&red[1][n_l][m_l0];
    float4 s2 = *(const float4*)&red[2][n_l][m_l0];
    float4 s3 = *(const float4*)&red[3][n_l][m_l0];

    const int   n_g = n0 + n_l;
    const float cA  = cOut[b * 512 + n_g];
    const float4 cB = *(const float4*)&cOut[1024 + b * 512 + m0 + m_l0];

    float4 res;
    {
        float tot[4] = { s0.x + s1.x + s2.x + s3.x,
                         s0.y + s1.y + s2.y + s3.y,
                         s0.z + s1.z + s2.z + s3.z,
                         s0.w + s1.w + s2.w + s3.w };
        const float cb[4] = { cB.x, cB.y, cB.z, cB.w };
        float* rp = (float*)&res;
        #pragma unroll
        for (int e = 0; e < 4; ++e) {
            float dsq = 0.5f * (tot[e] + cA + cb[e]);
            dsq = fminf(fmaxf(dsq, 1e-6f), 1e6f);
            rp[e] = sqrtf(dsq);
        }
    }
    *(float4*)&out[((size_t)(b * 512 + n_g)) * 512 + m0 + m_l0] = res;
}

// ---------------------------------------------------------------------------
extern "C" void kernel_launch(void* const* d_in, const int* in_sizes, int n_in,
                              void* d_out, int out_size, void* d_ws, size_t ws_size,
                              hipStream_t stream)
{
    const float* Q  = (const float*)d_in[0];
    const float* K  = (const float*)d_in[1];
    const float* w1 = (const float*)d_in[2];
    const float* b1 = (const float*)d_in[3];
    const float* w2 = (const float*)d_in[4];
    const float* b2 = (const float*)d_in[5];
    float* out = (float*)d_out;

    unsigned short* featA = (unsigned short*)d_ws;            // [1024][1152] bf16
    unsigned short* featB = featA + (size_t)1024 * KF;        // [1024][1152] bf16
    float* cOut = (float*)(featB + (size_t)1024 * KF);        // [2048] fp32
    float* raw  = cOut + 2048;                                // [2048][1024] fp32 (probe; unread)

    k_raw<<<dim3(64, 4), dim3(256), 0, stream>>>(Q, K, w1, b1, w2, b2, raw);
    k_feat<<<dim3(2048 / RPB), dim3(256), 0, stream>>>(Q, K, w1, b1, w2, b2, featA, featB, cOut);
    k_gemm<<<dim3(512), dim3(256), 0, stream>>>(featA, featB, cOut, out);
}

// Round 9
// 108.779 us; speedup vs baseline: 1.0478x; 1.0446x over previous
//
#include <hip/hip_runtime.h>
#include <math.h>

namespace {
constexpr int KF  = 1152;   // padded feature dim (1120 used + 32 zeros)
constexpr int RPB = 8;      // rows per k_feat block (grid 256 = ONE round/CU)
}

typedef __bf16 v8bf __attribute__((ext_vector_type(8)));
typedef float  v4f  __attribute__((ext_vector_type(4)));

__device__ __forceinline__ unsigned short f2bf(float f) {
    union { float f; unsigned u; } v; v.f = f;
    unsigned r = v.u + 0x7FFFu + ((v.u >> 16) & 1u);
    return (unsigned short)(r >> 16);
}

__device__ __forceinline__ v8bf as_v8bf(uint4 u) {
    union { uint4 u; v8bf b; } c; c.u = u; return c.b;
}

// ---------------------------------------------------------------------------
// K1: per-row feature builder. Round-9: RPB 4->8, grid 256.
// Model (fits R1=43us@512blk, R5=105us@1024blk, R7~R8): k_feat time ~
// (serial block-rounds per CU) x (per-block w2-stream stall ~21-26us).
// 256 blocks = 1 block/CU = ONE round; aggregate w2 traffic halves (64MB).
// Tail work/block doubles, total tail constant. LDS 59KB. Raw-stage
// processes rows in 2 groups of 4 under each w2 quad to bound VGPR (~120,
// no forced launch_bounds — R4's spill lesson). Per-element FMA order
// (k ascending, b2 init) bitwise-identical to the verified kernel.
// ---------------------------------------------------------------------------
__global__ __launch_bounds__(256) void k_feat(
    const float* __restrict__ Q, const float* __restrict__ K,
    const float* __restrict__ w1, const float* __restrict__ b1,
    const float* __restrict__ w2, const float* __restrict__ b2,
    unsigned short* __restrict__ featA, unsigned short* __restrict__ featB,
    float* __restrict__ cOut)
{
    __shared__ __attribute__((aligned(16))) float x_s[RPB][32];
    __shared__ __attribute__((aligned(16))) float h_s[RPB][64];
    __shared__ __attribute__((aligned(16))) float L_s[RPB][32][36];
    __shared__ __attribute__((aligned(16))) float G_s[RPB][528];   // col-major packed
    __shared__ __attribute__((aligned(16))) float u_s[RPB][32];
    __shared__ unsigned short tri_s[528];                          // (i<<8)|j

    const int t  = threadIdx.x;
    const int g0 = blockIdx.x * RPB;

    // ---- triangular index table (once)
    for (int pr = t; pr < 528; pr += 256) {
        int j = (int)((65.0f - sqrtf(4225.0f - 8.0f * (float)pr)) * 0.5f);
        while (j > 0 && j * (65 - j) / 2 > pr) --j;
        while ((j + 1) * (64 - j) / 2 <= pr) ++j;
        int i = j + (pr - j * (65 - j) / 2);
        tri_s[pr] = (unsigned short)((i << 8) | j);
    }
    // ---- load x: RPB*32 = 256 = blockDim, 1 elem/thread
    {
        int r = t >> 5, i = t & 31;
        int g = g0 + r;
        const float* src = (g < 1024) ? (Q + (size_t)g * 32)
                                      : (K + (size_t)(g - 1024) * 32);
        x_s[r][i] = src[i];
    }
    __syncthreads();

    // ---- h = silu(x @ w1 + b1): RPB*64 = 512 outputs, 2/thread
    {
        int j = t & 63;
        #pragma unroll
        for (int ro = 0; ro < 2; ++ro) {
            int r = (t >> 6) + ro * 4;
            float z = b1[j];
            #pragma unroll
            for (int i = 0; i < 32; ++i) z = fmaf(x_s[r][i], w1[i * 64 + j], z);
            h_s[r][j] = z / (1.0f + __expf(-z));
        }
    }
    __syncthreads();

    // ---- raw = h @ w2 + b2 -> L.  Thread t owns p-quad [4t,4t+4), all 8 rows.
    // Row-groups of 4 under each w2 quad bound VGPR pressure.
    {
        const int p4 = t * 4;
        float acc[RPB][4];
        float4 bq = *(const float4*)&b2[p4];
        #pragma unroll
        for (int r = 0; r < RPB; ++r) {
            acc[r][0] = bq.x; acc[r][1] = bq.y; acc[r][2] = bq.z; acc[r][3] = bq.w;
        }
        for (int jb = 0; jb < 8; ++jb) {
            float4 wq[8];
            #pragma unroll
            for (int jj = 0; jj < 8; ++jj)
                wq[jj] = *(const float4*)&w2[(size_t)(jb * 8 + jj) * 1024 + p4];
            #pragma unroll
            for (int gr = 0; gr < 2; ++gr) {
                float h8[4][8];
                #pragma unroll
                for (int r4 = 0; r4 < 4; ++r4) {
                    *(float4*)&h8[r4][0] = *(const float4*)&h_s[gr * 4 + r4][jb * 8 + 0];
                    *(float4*)&h8[r4][4] = *(const float4*)&h_s[gr * 4 + r4][jb * 8 + 4];
                }
                #pragma unroll
                for (int jj = 0; jj < 8; ++jj) {
                    #pragma unroll
                    for (int r4 = 0; r4 < 4; ++r4) {
                        const int r = gr * 4 + r4;
                        acc[r][0] = fmaf(h8[r4][jj], wq[jj].x, acc[r][0]);
                        acc[r][1] = fmaf(h8[r4][jj], wq[jj].y, acc[r][1]);
                        acc[r][2] = fmaf(h8[r4][jj], wq[jj].z, acc[r][2]);
                        acc[r][3] = fmaf(h8[r4][jj], wq[jj].w, acc[r][3]);
                    }
                }
            }
        }
        const int i  = p4 >> 5;
        const int j0 = p4 & 31;
        #pragma unroll
        for (int r = 0; r < RPB; ++r) {
            float4 lv;
            float* lvp = (float*)&lv;
            #pragma unroll
            for (int e = 0; e < 4; ++e) {
                int j = j0 + e;
                float raw = acc[r][e];
                float ex = __expf(0.4f * raw);
                float c5 = 5.0f * (ex - 1.0f) / (ex + 1.0f);   // 5*tanh(raw/5)
                float val;
                if (i < j)       val = 0.0f;
                else if (i == j) { float z = c5 + 1.0f; val = log1pf(__expf(z)) + 1e-4f; }
                else             val = c5;
                lvp[e] = val;
            }
            *(float4*)&L_s[r][i][j0] = lv;
        }
    }
    __syncthreads();

    // ---- G = L L^T (lower triangle, packed column-major)
    for (int idx = t; idx < RPB * 528; idx += 256) {
        int r  = idx / 528;
        int pr = idx - r * 528;
        int tv = tri_s[pr];
        int i = tv >> 8, j = tv & 255;
        const float* Li = &L_s[r][i][0];
        const float* Lj = &L_s[r][j][0];
        float s = 0.0f;
        int nf = (j + 1) >> 2;
        for (int q = 0; q < nf; ++q) {
            float4 a  = *(const float4*)&Li[q * 4];
            float4 bb = *(const float4*)&Lj[q * 4];
            s += a.x * bb.x + a.y * bb.y + a.z * bb.z + a.w * bb.w;
        }
        for (int tt = nf * 4; tt <= j; ++tt) s = fmaf(Li[tt], Lj[tt], s);
        G_s[r][pr] = s;
    }
    __syncthreads();

    // ---- u = G x: RPB*32 = 256 = blockDim, 1/thread
    {
        int r = t >> 5, i = t & 31;
        float s = 0.0f;
        #pragma unroll
        for (int j = 0; j < 32; ++j) {
            float gv = (j <= i) ? G_s[r][j * (65 - j) / 2 + i - j]
                                : G_s[r][i * (65 - i) / 2 + j - i];
            s = fmaf(gv, x_s[r][j], s);
        }
        u_s[r][i] = s;
    }
    __syncthreads();

    // ---- c = u . x
    if (t < RPB) {
        float s = 0.0f;
        #pragma unroll
        for (int i = 0; i < 32; ++i) s = fmaf(u_s[t][i], x_s[t][i], s);
        cOut[g0 + t] = s;
    }

    // ---- feature write: quads of 4 bf16, packed uint2 stores (coalesced).
    for (int idx = t; idx < RPB * (KF / 4); idx += 256) {
        int r   = idx / (KF / 4);
        int q   = idx - r * (KF / 4);
        int pos = q * 4;
        int g   = g0 + r;
        bool isA = (g < 1024);
        unsigned short* dst = isA ? (featA + (size_t)g * KF)
                                  : (featB + (size_t)(g - 1024) * KF);
        unsigned short ev[4];
        #pragma unroll
        for (int e = 0; e < 4; ++e) {
            int p = pos + e;
            float va;
            if (p < 1056) {
                int pr = (p < 528) ? p : p - 528;
                bool wantG = (p < 528) ? isA : !isA;
                int tv = tri_s[pr];
                int i = tv >> 8, j = tv & 255;
                float gv = G_s[r][pr] * ((i == j) ? 1.0f : 2.0f);
                float ov = x_s[r][i] * x_s[r][j];
                va = wantG ? gv : ov;
            } else if (p < 1088) {
                int i = p - 1056;
                va = isA ? u_s[r][i] : -2.0f * x_s[r][i];
            } else if (p < 1120) {
                int i = p - 1088;
                va = isA ? x_s[r][i] : -2.0f * u_s[r][i];
            } else {
                va = 0.0f;   // ws re-poisoned 0xAA — pad must be written
            }
            ev[e] = f2bf(va);
        }
        uint2 w;
        w.x = (unsigned)ev[0] | ((unsigned)ev[1] << 16);
        w.y = (unsigned)ev[2] | ((unsigned)ev[3] << 16);
        *(uint2*)(dst + pos) = w;
    }
}

// ---------------------------------------------------------------------------
// K2: out = sqrt(clip(0.5*(cA+cB+A.B))). Verified round-1 split-K MFMA GEMM
// + fused epilogue (unchanged). 512 blocks, 4 waves/tile, XCD swizzle.
// ---------------------------------------------------------------------------
__global__ __launch_bounds__(256) void k_gemm(
    const unsigned short* __restrict__ featA,
    const unsigned short* __restrict__ featB,
    const float* __restrict__ cOut,
    float* __restrict__ out)
{
    __shared__ __attribute__((aligned(16))) float red[4][32][36];  // +4 pad

    const int t    = threadIdx.x;
    const int lane = t & 63;
    const int w    = t >> 6;          // wave id 0..3 = K-chunk id

    const int lin = blockIdx.x;
    const int swz = (lin & 7) * 64 + (lin >> 3);
    const int m0 = (swz & 15) * 32;
    const int n0 = ((swz >> 4) & 15) * 32;
    const int b  = swz >> 8;

    const int fr = lane & 15;
    const int fq = lane >> 4;
    const int kbase = w * 288 + fq * 8;

    const unsigned short* pA0 = featA + (size_t)(b * 512 + n0 + fr) * KF + kbase;
    const unsigned short* pA1 = pA0 + (size_t)16 * KF;
    const unsigned short* pB0 = featB + (size_t)(b * 512 + m0 + fr) * KF + kbase;
    const unsigned short* pB1 = pB0 + (size_t)16 * KF;

    v4f acc00 = {0,0,0,0}, acc01 = {0,0,0,0}, acc10 = {0,0,0,0}, acc11 = {0,0,0,0};

    uint4 bA0[4], bA1[4], bB0[4], bB1[4];
    #pragma unroll
    for (int s = 0; s < 4; ++s) {
        bA0[s] = *(const uint4*)(pA0 + s * 32);
        bA1[s] = *(const uint4*)(pA1 + s * 32);
        bB0[s] = *(const uint4*)(pB0 + s * 32);
        bB1[s] = *(const uint4*)(pB1 + s * 32);
    }

    #pragma unroll
    for (int s = 0; s < 9; ++s) {
        const int slot = s & 3;
        v8bf a0  = as_v8bf(bA0[slot]);
        v8bf a1  = as_v8bf(bA1[slot]);
        v8bf b0v = as_v8bf(bB0[slot]);
        v8bf b1v = as_v8bf(bB1[slot]);
        const int kn = s + 4;
        if (kn < 9) {
            bA0[slot] = *(const uint4*)(pA0 + kn * 32);
            bA1[slot] = *(const uint4*)(pA1 + kn * 32);
            bB0[slot] = *(const uint4*)(pB0 + kn * 32);
            bB1[slot] = *(const uint4*)(pB1 + kn * 32);
        }
        acc00 = __builtin_amdgcn_mfma_f32_16x16x32_bf16(a0, b0v, acc00, 0, 0, 0);
        acc01 = __builtin_amdgcn_mfma_f32_16x16x32_bf16(a0, b1v, acc01, 0, 0, 0);
        acc10 = __builtin_amdgcn_mfma_f32_16x16x32_bf16(a1, b0v, acc10, 0, 0, 0);
        acc11 = __builtin_amdgcn_mfma_f32_16x16x32_bf16(a1, b1v, acc11, 0, 0, 0);
    }

    #pragma unroll
    for (int v = 0; v < 4; ++v) {
        red[w][fq * 4 + v][fr]           = acc00[v];
        red[w][fq * 4 + v][fr + 16]      = acc01[v];
        red[w][16 + fq * 4 + v][fr]      = acc10[v];
        red[w][16 + fq * 4 + v][fr + 16] = acc11[v];
    }
    __syncthreads();

    const int n_l  = t >> 3;
    const int m_l0 = (t & 7) * 4;
    float4 s0 = *(const float4*)&red[0][n_l][m_l0];
    float4 s1 = *(const float4*)&red[1][n_l][m_l0];
    float4 s2 = *(const float4*)&red[2][n_l][m_l0];
    float4 s3 = *(const float4*)&red[3][n_l][m_l0];

    const int   n_g = n0 + n_l;
    const float cA  = cOut[b * 512 + n_g];
    const float4 cB = *(const float4*)&cOut[1024 + b * 512 + m0 + m_l0];

    float4 res;
    {
        float tot[4] = { s0.x + s1.x + s2.x + s3.x,
                         s0.y + s1.y + s2.y + s3.y,
                         s0.z + s1.z + s2.z + s3.z,
                         s0.w + s1.w + s2.w + s3.w };
        const float cb[4] = { cB.x, cB.y, cB.z, cB.w };
        float* rp = (float*)&res;
        #pragma unroll
        for (int e = 0; e < 4; ++e) {
            float dsq = 0.5f * (tot[e] + cA + cb[e]);
            dsq = fminf(fmaxf(dsq, 1e-6f), 1e6f);
            rp[e] = sqrtf(dsq);
        }
    }
    *(float4*)&out[((size_t)(b * 512 + n_g)) * 512 + m0 + m_l0] = res;
}

// ---------------------------------------------------------------------------
extern "C" void kernel_launch(void* const* d_in, const int* in_sizes, int n_in,
                              void* d_out, int out_size, void* d_ws, size_t ws_size,
                              hipStream_t stream)
{
    const float* Q  = (const float*)d_in[0];
    const float* K  = (const float*)d_in[1];
    const float* w1 = (const float*)d_in[2];
    const float* b1 = (const float*)d_in[3];
    const float* w2 = (const float*)d_in[4];
    const float* b2 = (const float*)d_in[5];
    float* out = (float*)d_out;

    unsigned short* featA = (unsigned short*)d_ws;            // [1024][1152] bf16
    unsigned short* featB = featA + (size_t)1024 * KF;        // [1024][1152] bf16
    float* cOut = (float*)(featB + (size_t)1024 * KF);        // [2048] fp32

    k_feat<<<dim3(2048 / RPB), dim3(256), 0, stream>>>(Q, K, w1, b1, w2, b2, featA, featB, cOut);
    k_gemm<<<dim3(512), dim3(256), 0, stream>>>(featA, featB, cOut, out);
}

// Round 10
// 100.659 us; speedup vs baseline: 1.1324x; 1.0807x over previous
//
#include <hip/hip_runtime.h>
#include <math.h>

namespace {
constexpr int KF  = 1152;   // padded feature dim (1120 used + 32 zeros)
constexpr int RPB = 2;      // rows per k_feat block (grid 1024, 4 blk/CU resident)
}

typedef __bf16 v8bf __attribute__((ext_vector_type(8)));
typedef float  v4f  __attribute__((ext_vector_type(4)));

__device__ __forceinline__ unsigned short f2bf(float f) {
    union { float f; unsigned u; } v; v.f = f;
    unsigned r = v.u + 0x7FFFu + ((v.u >> 16) & 1u);
    return (unsigned short)(r >> 16);
}

__device__ __forceinline__ v8bf as_v8bf(uint4 u) {
    union { uint4 u; v8bf b; } c; c.u = u; return c.b;
}

// ---------------------------------------------------------------------------
// K1: per-row feature builder. Round-10 theory: VALU-issue + LDS-latency
// bound TAIL (raw FMAs, G=LL^T chains, u/feature index math) with only
// 2 waves/SIMD resident (VGPR=252 capped occupancy). Changes vs R5 base:
//  (1) launch_bounds(256,4): VGPR<=128 -> 4 blocks/CU resident, 2x hiding
//  (2) G-stage: fixed-trip 8x float4, fully unrolled (tril zeros -> exact)
//  (3) u-stage: rowoff LDS table replaces per-iter j*(65-j)/2 muls
//  (4) raw-stage: fully-upper quads (j0>i) skip the 512-FMA/64-load block
//      (their L outputs are the val=0 path) — bitwise-identical outputs
// ---------------------------------------------------------------------------
__global__ __launch_bounds__(256, 4) void k_feat(
    const float* __restrict__ Q, const float* __restrict__ K,
    const float* __restrict__ w1, const float* __restrict__ b1,
    const float* __restrict__ w2, const float* __restrict__ b2,
    unsigned short* __restrict__ featA, unsigned short* __restrict__ featB,
    float* __restrict__ cOut)
{
    __shared__ __attribute__((aligned(16))) float x_s[RPB][32];
    __shared__ __attribute__((aligned(16))) float h_s[RPB][64];
    __shared__ __attribute__((aligned(16))) float L_s[RPB][32][36];
    __shared__ __attribute__((aligned(16))) float G_s[RPB][528];   // col-major packed
    __shared__ __attribute__((aligned(16))) float u_s[RPB][32];
    __shared__ unsigned short tri_s[528];                          // (i<<8)|j
    __shared__ unsigned short rowoff_s[32];                        // j*(65-j)/2

    const int t  = threadIdx.x;
    const int g0 = blockIdx.x * RPB;

    // ---- triangular index + rowoff tables (once)
    for (int pr = t; pr < 528; pr += 256) {
        int j = (int)((65.0f - sqrtf(4225.0f - 8.0f * (float)pr)) * 0.5f);
        while (j > 0 && j * (65 - j) / 2 > pr) --j;
        while ((j + 1) * (64 - j) / 2 <= pr) ++j;
        int i = j + (pr - j * (65 - j) / 2);
        tri_s[pr] = (unsigned short)((i << 8) | j);
    }
    if (t < 32) rowoff_s[t] = (unsigned short)(t * (65 - t) / 2);

    // ---- load x
    if (t < RPB * 32) {
        int r = t >> 5, i = t & 31;
        int g = g0 + r;
        const float* src = (g < 1024) ? (Q + (size_t)g * 32)
                                      : (K + (size_t)(g - 1024) * 32);
        x_s[r][i] = src[i];
    }
    __syncthreads();

    // ---- h = silu(x @ w1 + b1): RPB*64 outputs, threads 0..127
    if (t < RPB * 64) {
        int r = t >> 6, j = t & 63;
        float z = b1[j];
        #pragma unroll
        for (int i = 0; i < 32; ++i) z = fmaf(x_s[r][i], w1[i * 64 + j], z);
        h_s[r][j] = z / (1.0f + __expf(-z));
    }
    __syncthreads();

    // ---- raw = h @ w2 + b2 -> L.  Thread t owns p-quad [4t,4t+4), all rows.
    // Fully-upper quads (j0 > i) skip the FMA/load block: outputs are val=0.
    {
        const int p4 = t * 4;
        const int i  = p4 >> 5;
        const int j0 = p4 & 31;
        float acc[RPB][4];
        float4 bq = *(const float4*)&b2[p4];
        #pragma unroll
        for (int r = 0; r < RPB; ++r) {
            acc[r][0] = bq.x; acc[r][1] = bq.y; acc[r][2] = bq.z; acc[r][3] = bq.w;
        }
        if (j0 <= i) {   // quad contains at least one lower/diag element
            for (int jb = 0; jb < 8; ++jb) {
                float h8[RPB][8];
                #pragma unroll
                for (int r = 0; r < RPB; ++r) {
                    *(float4*)&h8[r][0] = *(const float4*)&h_s[r][jb * 8 + 0];
                    *(float4*)&h8[r][4] = *(const float4*)&h_s[r][jb * 8 + 4];
                }
                #pragma unroll
                for (int jj = 0; jj < 8; ++jj) {
                    float4 w = *(const float4*)&w2[(size_t)(jb * 8 + jj) * 1024 + p4];
                    #pragma unroll
                    for (int r = 0; r < RPB; ++r) {
                        acc[r][0] = fmaf(h8[r][jj], w.x, acc[r][0]);
                        acc[r][1] = fmaf(h8[r][jj], w.y, acc[r][1]);
                        acc[r][2] = fmaf(h8[r][jj], w.z, acc[r][2]);
                        acc[r][3] = fmaf(h8[r][jj], w.w, acc[r][3]);
                    }
                }
            }
        }
        #pragma unroll
        for (int r = 0; r < RPB; ++r) {
            float4 lv;
            float* lvp = (float*)&lv;
            #pragma unroll
            for (int e = 0; e < 4; ++e) {
                int j = j0 + e;
                float raw = acc[r][e];
                float ex = __expf(0.4f * raw);
                float c5 = 5.0f * (ex - 1.0f) / (ex + 1.0f);   // 5*tanh(raw/5)
                float val;
                if (i < j)       val = 0.0f;
                else if (i == j) { float z = c5 + 1.0f; val = log1pf(__expf(z)) + 1e-4f; }
                else             val = c5;
                lvp[e] = val;
            }
            *(float4*)&L_s[r][i][j0] = lv;
        }
    }
    __syncthreads();

    // ---- G = L L^T: fixed-trip, fully unrolled (tril zeros make extra
    // products exact 0; association within the last partial group changes
    // by <=1ulp vs the old remainder loop)
    for (int idx = t; idx < RPB * 528; idx += 256) {
        int r  = idx / 528;
        int pr = idx - r * 528;
        int tv = tri_s[pr];
        int i = tv >> 8, j = tv & 255;
        const float* Li = &L_s[r][i][0];
        const float* Lj = &L_s[r][j][0];
        float s = 0.0f;
        #pragma unroll
        for (int q = 0; q < 8; ++q) {
            float4 a  = *(const float4*)&Li[q * 4];
            float4 bb = *(const float4*)&Lj[q * 4];
            s += a.x * bb.x + a.y * bb.y + a.z * bb.z + a.w * bb.w;
        }
        G_s[r][pr] = s;
    }
    __syncthreads();

    // ---- u = G x (rowoff table; threads 0..63)
    if (t < RPB * 32) {
        int r = t >> 5, i = t & 31;
        const int base_i = (int)rowoff_s[i] - i;
        float s = 0.0f;
        #pragma unroll
        for (int j = 0; j < 32; ++j) {
            int gidx = (j <= i) ? ((int)rowoff_s[j] + i - j) : (base_i + j);
            s = fmaf(G_s[r][gidx], x_s[r][j], s);
        }
        u_s[r][i] = s;
    }
    __syncthreads();

    // ---- c = u . x
    if (t < RPB) {
        float s = 0.0f;
        #pragma unroll
        for (int i = 0; i < 32; ++i) s = fmaf(u_s[t][i], x_s[t][i], s);
        cOut[g0 + t] = s;
    }

    // ---- feature write: quads of 4 bf16, packed uint2 stores (coalesced).
    for (int idx = t; idx < RPB * (KF / 4); idx += 256) {
        int r   = idx / (KF / 4);
        int q   = idx - r * (KF / 4);
        int pos = q * 4;
        int g   = g0 + r;
        bool isA = (g < 1024);
        unsigned short* dst = isA ? (featA + (size_t)g * KF)
                                  : (featB + (size_t)(g - 1024) * KF);
        unsigned short ev[4];
        #pragma unroll
        for (int e = 0; e < 4; ++e) {
            int p = pos + e;
            float va;
            if (p < 1056) {
                int pr = (p < 528) ? p : p - 528;
                bool wantG = (p < 528) ? isA : !isA;
                int tv = tri_s[pr];
                int i = tv >> 8, j = tv & 255;
                float gv = G_s[r][pr] * ((i == j) ? 1.0f : 2.0f);
                float ov = x_s[r][i] * x_s[r][j];
                va = wantG ? gv : ov;
            } else if (p < 1088) {
                int i = p - 1056;
                va = isA ? u_s[r][i] : -2.0f * x_s[r][i];
            } else if (p < 1120) {
                int i = p - 1088;
                va = isA ? x_s[r][i] : -2.0f * u_s[r][i];
            } else {
                va = 0.0f;   // ws re-poisoned 0xAA — pad must be written
            }
            ev[e] = f2bf(va);
        }
        uint2 w;
        w.x = (unsigned)ev[0] | ((unsigned)ev[1] << 16);
        w.y = (unsigned)ev[2] | ((unsigned)ev[3] << 16);
        *(uint2*)(dst + pos) = w;
    }
}

// ---------------------------------------------------------------------------
// K2: out = sqrt(clip(0.5*(cA+cB+A.B))). Verified round-1 split-K MFMA GEMM
// + fused epilogue (unchanged). 512 blocks, 4 waves/tile, XCD swizzle.
// ---------------------------------------------------------------------------
__global__ __launch_bounds__(256) void k_gemm(
    const unsigned short* __restrict__ featA,
    const unsigned short* __restrict__ featB,
    const float* __restrict__ cOut,
    float* __restrict__ out)
{
    __shared__ __attribute__((aligned(16))) float red[4][32][36];  // +4 pad

    const int t    = threadIdx.x;
    const int lane = t & 63;
    const int w    = t >> 6;          // wave id 0..3 = K-chunk id

    const int lin = blockIdx.x;
    const int swz = (lin & 7) * 64 + (lin >> 3);
    const int m0 = (swz & 15) * 32;
    const int n0 = ((swz >> 4) & 15) * 32;
    const int b  = swz >> 8;

    const int fr = lane & 15;
    const int fq = lane >> 4;
    const int kbase = w * 288 + fq * 8;

    const unsigned short* pA0 = featA + (size_t)(b * 512 + n0 + fr) * KF + kbase;
    const unsigned short* pA1 = pA0 + (size_t)16 * KF;
    const unsigned short* pB0 = featB + (size_t)(b * 512 + m0 + fr) * KF + kbase;
    const unsigned short* pB1 = pB0 + (size_t)16 * KF;

    v4f acc00 = {0,0,0,0}, acc01 = {0,0,0,0}, acc10 = {0,0,0,0}, acc11 = {0,0,0,0};

    uint4 bA0[4], bA1[4], bB0[4], bB1[4];
    #pragma unroll
    for (int s = 0; s < 4; ++s) {
        bA0[s] = *(const uint4*)(pA0 + s * 32);
        bA1[s] = *(const uint4*)(pA1 + s * 32);
        bB0[s] = *(const uint4*)(pB0 + s * 32);
        bB1[s] = *(const uint4*)(pB1 + s * 32);
    }

    #pragma unroll
    for (int s = 0; s < 9; ++s) {
        const int slot = s & 3;
        v8bf a0  = as_v8bf(bA0[slot]);
        v8bf a1  = as_v8bf(bA1[slot]);
        v8bf b0v = as_v8bf(bB0[slot]);
        v8bf b1v = as_v8bf(bB1[slot]);
        const int kn = s + 4;
        if (kn < 9) {
            bA0[slot] = *(const uint4*)(pA0 + kn * 32);
            bA1[slot] = *(const uint4*)(pA1 + kn * 32);
            bB0[slot] = *(const uint4*)(pB0 + kn * 32);
            bB1[slot] = *(const uint4*)(pB1 + kn * 32);
        }
        acc00 = __builtin_amdgcn_mfma_f32_16x16x32_bf16(a0, b0v, acc00, 0, 0, 0);
        acc01 = __builtin_amdgcn_mfma_f32_16x16x32_bf16(a0, b1v, acc01, 0, 0, 0);
        acc10 = __builtin_amdgcn_mfma_f32_16x16x32_bf16(a1, b0v, acc10, 0, 0, 0);
        acc11 = __builtin_amdgcn_mfma_f32_16x16x32_bf16(a1, b1v, acc11, 0, 0, 0);
    }

    #pragma unroll
    for (int v = 0; v < 4; ++v) {
        red[w][fq * 4 + v][fr]           = acc00[v];
        red[w][fq * 4 + v][fr + 16]      = acc01[v];
        red[w][16 + fq * 4 + v][fr]      = acc10[v];
        red[w][16 + fq * 4 + v][fr + 16] = acc11[v];
    }
    __syncthreads();

    const int n_l  = t >> 3;
    const int m_l0 = (t & 7) * 4;
    float4 s0 = *(const float4*)&red[0][n_l][m_l0];
    float4 s1 = *(const float4*)&red[1][n_l][m_l0];
    float4 s2 = *(const float4*)&red[2][n_l][m_l0];
    float4 s3 = *(const float4*)&red[3][n_l][m_l0];

    const int   n_g = n0 + n_l;
    const float cA  = cOut[b * 512 + n_g];
    const float4 cB = *(const float4*)&cOut[1024 + b * 512 + m0 + m_l0];

    float4 res;
    {
        float tot[4] = { s0.x + s1.x + s2.x + s3.x,
                         s0.y + s1.y + s2.y + s3.y,
                         s0.z + s1.z + s2.z + s3.z,
                         s0.w + s1.w + s2.w + s3.w };
        const float cb[4] = { cB.x, cB.y, cB.z, cB.w };
        float* rp = (float*)&res;
        #pragma unroll
        for (int e = 0; e < 4; ++e) {
            float dsq = 0.5f * (tot[e] + cA + cb[e]);
            dsq = fminf(fmaxf(dsq, 1e-6f), 1e6f);
            rp[e] = sqrtf(dsq);
        }
    }
    *(float4*)&out[((size_t)(b * 512 + n_g)) * 512 + m0 + m_l0] = res;
}

// ---------------------------------------------------------------------------
extern "C" void kernel_launch(void* const* d_in, const int* in_sizes, int n_in,
                              void* d_out, int out_size, void* d_ws, size_t ws_size,
                              hipStream_t stream)
{
    const float* Q  = (const float*)d_in[0];
    const float* K  = (const float*)d_in[1];
    const float* w1 = (const float*)d_in[2];
    const float* b1 = (const float*)d_in[3];
    const float* w2 = (const float*)d_in[4];
    const float* b2 = (const float*)d_in[5];
    float* out = (float*)d_out;

    unsigned short* featA = (unsigned short*)d_ws;            // [1024][1152] bf16
    unsigned short* featB = featA + (size_t)1024 * KF;        // [1024][1152] bf16
    float* cOut = (float*)(featB + (size_t)1024 * KF);        // [2048] fp32

    k_feat<<<dim3(2048 / RPB), dim3(256), 0, stream>>>(Q, K, w1, b1, w2, b2, featA, featB, cOut);
    k_gemm<<<dim3(512), dim3(256), 0, stream>>>(featA, featB, cOut, out);
}